// Round 10
// baseline (472.248 us; speedup 1.0000x reference)
//
#include <hip/hip_runtime.h>
#include <hip/hip_bf16.h>
#include <math.h>

// =============================================================================
// v10: conv1-5 = split-fp16 2-pass MFMA implicit-GEMM (v9 skeleton) with
//   B-PREFETCH DISTANCE 2: loadB(s+2) issued at step s into alternating
//   register sets (manual 2x unroll -> static regs), stored to LDS at s+1.
//   Doubles the global-load latency cover via ILP -- targets the grid-starved
//   mid convs (conv2-5 at <=2 blocks/CU) and conv1's cold fp32 reads.
//   LDS buffers / barrier structure / index math identical to verified v9.
// =============================================================================

typedef __attribute__((ext_vector_type(8))) _Float16 f16x8;  // 8 fp16 in 4 VGPRs
typedef __attribute__((ext_vector_type(4))) float f32x4;

__device__ __forceinline__ unsigned short f2h_bits(float f) {
    union { _Float16 h; unsigned short u; } cv;
    cv.h = (_Float16)f;                      // v_cvt_f16_f32, RNE
    return cv.u;
}

__device__ __forceinline__ void stage16(const void* g, void* l) {
    __builtin_amdgcn_global_load_lds(
        (const __attribute__((address_space(1))) unsigned int*)g,
        (__attribute__((address_space(3))) unsigned int*)l, 16, 0, 0);
}

// ---------------------------------------------------------------------------
// A image (per K-step of 32): [step][half(hi/lo)][mg(6)][lane(64)][j(8)] fp16.
// B LDS image (per step): NCI rows of RD dwords; dword d of row = elements
// (2*(t0+d), 2*(t0+d)+1).  Lane (quad q,l16) frag = 4 dwords at
// cil*RD + wc0 + l16 + dwo + nt*16;  cil=(q*8)/KP, dwo=((q*8)%KP)/2.
// ---------------------------------------------------------------------------
template<int KP, int CI, int NBLK, bool IN_FP32, bool RELU, bool OUT_F16, bool POOL>
__global__ __launch_bounds__(256)
void conv_mfma10(const unsigned short* __restrict__ xh,
                 const unsigned short* __restrict__ wpk,
                 const float* __restrict__ bias,
                 unsigned short* __restrict__ yh,
                 float* __restrict__ yf,
                 int Tin, int Tout)
{
    constexpr int CO    = 96;
    constexpr int STEPS = CI * KP / 32;
    constexpr int NCI   = 32 / KP;
    constexpr int RD    = NBLK + KP / 2 + 2;
    constexpr int NTW   = NBLK / 64;
    constexpr int TOT   = NCI * RD;
    constexpr int NIT   = (TOT + 255) / 256;

    __shared__ __align__(16) unsigned short As[2][6144];   // 24 KB A dbuf
    __shared__ unsigned int Bs[2][TOT];                    // B dbuf (fp16 pairs)

    const int tid  = threadIdx.x;
    const int lane = tid & 63;
    const int wave = tid >> 6;
    const int quad = lane >> 4;
    const int l16  = lane & 15;
    const int wc0  = wave * (NBLK / 4);

    const int nT = (Tout + NBLK - 1) / NBLK;
    const int b  = blockIdx.x / nT;
    const int t0 = (blockIdx.x % nT) * NBLK;

    const float* xf = (const float*)xh;
    const unsigned int* xb = (const unsigned int*)xh + (((size_t)b * CI * Tin) >> 1);
    const int rowd = Tin >> 1;

    auto stageA = [&](int s, int buf) {
        const char* g = (const char*)(wpk + (size_t)s * 6144) + (size_t)lane * 16;
        char* l = (char*)&As[buf][0] + (size_t)lane * 16;
        #pragma unroll
        for (int i = 0; i < 3; ++i) {
            int seg = i * 4 + wave;
            stage16(g + seg * 1024, l + seg * 1024);
        }
    };

    unsigned int rA[NIT], rB[NIT];
    auto loadB = [&](int s, unsigned int* r) {
        const int ci0 = s * NCI;
        #pragma unroll
        for (int it = 0; it < NIT; ++it) {
            int i = tid + it * 256;
            if (i < TOT) {
                int r_ = i / RD, d = i - r_ * RD;      // RD constexpr
                if (IN_FP32) {
                    int e = 2 * (t0 + d);
                    if (e > Tin - 2) e = Tin - 2;      // clamp: padded-tap cols only
                    const float* src = xf + ((size_t)b * CI + ci0 + r_) * Tin + e;
                    float2 v = *(const float2*)src;
                    r[it] = (unsigned int)f2h_bits(v.x)
                          | ((unsigned int)f2h_bits(v.y) << 16);
                } else {
                    r[it] = *(xb + (size_t)(ci0 + r_) * rowd + t0 + d);
                }
            }
        }
    };
    auto storeB = [&](const unsigned int* r, int buf) {
        #pragma unroll
        for (int it = 0; it < NIT; ++it) {
            int i = tid + it * 256;
            if (i < TOT) Bs[buf][i] = r[it];
        }
    };

    f32x4 acc[6][NTW];
    #pragma unroll
    for (int mt = 0; mt < 6; ++mt)
        #pragma unroll
        for (int nt = 0; nt < NTW; ++nt) acc[mt][nt] = (f32x4)0.f;

    const int cil = (quad * 8) / KP;
    const int dwo = ((quad * 8) % KP) >> 1;

    auto compute = [&](int buf) {
        f16x8 Ah[6], Al[6];
        #pragma unroll
        for (int mt = 0; mt < 6; ++mt) {
            Ah[mt] = *(const f16x8*)&As[buf][(mt) * 512 + lane * 8];
            Al[mt] = *(const f16x8*)&As[buf][(6 + mt) * 512 + lane * 8];
        }
        const unsigned int* bp = &Bs[buf][cil * RD + wc0 + l16 + dwo];
        #pragma unroll
        for (int nt = 0; nt < NTW; ++nt) {
            union { unsigned int u[4]; f16x8 v; } Bv;
            #pragma unroll
            for (int p = 0; p < 4; ++p) Bv.u[p] = bp[nt * 16 + p];
            #pragma unroll
            for (int mt = 0; mt < 6; ++mt)
                acc[mt][nt] = __builtin_amdgcn_mfma_f32_16x16x32_f16(Ah[mt], Bv.v, acc[mt][nt], 0, 0, 0);
            #pragma unroll
            for (int mt = 0; mt < 6; ++mt)
                acc[mt][nt] = __builtin_amdgcn_mfma_f32_16x16x32_f16(Al[mt], Bv.v, acc[mt][nt], 0, 0, 0);
        }
    };

    // prologue: Bs[0] <- data(0); rA <- data(1)
    loadB(0, rA);
    storeB(rA, 0);
    if (STEPS > 1) loadB(1, rA);
    stageA(0, 0);
    __syncthreads();

    for (int s = 0; s < STEPS; s += 2) {
        // even step s: reads As[0], Bs[0]; rA holds data(s+1)
        if (s + 2 < STEPS) loadB(s + 2, rB);
        if (s + 1 < STEPS) stageA(s + 1, 1);
        compute(0);
        if (s + 1 < STEPS) storeB(rA, 1);
        __syncthreads();
        if (s + 1 >= STEPS) break;
        // odd step s+1: reads As[1], Bs[1]; rB holds data(s+2)
        if (s + 3 < STEPS) loadB(s + 3, rA);
        if (s + 2 < STEPS) stageA(s + 2, 0);
        compute(1);
        if (s + 2 < STEPS) storeB(rB, 0);
        __syncthreads();
    }

    // epilogue: C/D layout col=l16 (t), row = quad*4+reg
    #pragma unroll
    for (int mt = 0; mt < 6; ++mt) {
        #pragma unroll
        for (int r = 0; r < 4; ++r) {
            int o = mt * 16 + quad * 4 + r;
            float bv = bias[o];
            #pragma unroll
            for (int nt = 0; nt < NTW; ++nt) {
                int t = t0 + wc0 + nt * 16 + l16;
                float v = acc[mt][nt][r] + bv;
                if (RELU) v = fmaxf(v, 0.f);
                if (POOL) {
                    float sum = v + __shfl_xor(v, 1, 64);
                    if ((lane & 1) == 0 && t + 1 < Tout) {
                        float pr = fmaxf(0.5f * sum, 0.f);
                        size_t pidx = ((size_t)b * CO + o) * (Tout >> 1) + (t >> 1);
                        if (OUT_F16) yh[pidx] = f2h_bits(pr);
                        else         yf[pidx] = pr;
                    }
                } else if (t < Tout) {
                    size_t oidx = ((size_t)b * CO + o) * Tout + t;
                    if (OUT_F16) yh[oidx] = f2h_bits(v);
                    else         yf[oidx] = v;
                }
            }
        }
    }
}

// ---------------------------------------------------------------------------
// single repack kernel: 5 MFMA A-images (fp16 hi/lo) + 2 fp32 [ci][k][o]
// ---------------------------------------------------------------------------
__device__ __forceinline__ void repack_img(const float* __restrict__ w,
                                           unsigned short* __restrict__ wpk,
                                           int idx, int KP, int KW, int CI)
{
    int j = idx & 7, lane = (idx >> 3) & 63, g = idx >> 9;
    int c = g / 24, r = g % 24;
    int mt = r % 6, sh = r / 6;
    int half = sh & 1, s = sh >> 1;
    int S  = c * 2 + s;
    int kg = S * 32 + (lane >> 4) * 8 + j;
    int o  = mt * 16 + (lane & 15);
    int ci = kg / KP, k = kg % KP;
    float val = (k < KW) ? w[((size_t)o * CI + ci) * KW + k] : 0.f;
    _Float16 hh = (_Float16)val;
    union { _Float16 h; unsigned short u; } cv;
    cv.h = (half == 0) ? hh : (_Float16)(val - (float)hh);
    wpk[idx] = cv.u;
}
__device__ __forceinline__ void repack_okc(const float* __restrict__ w,
                                           float* __restrict__ wr,
                                           int idx, int CI, int K, int CO)
{
    int o = idx % CO; int rem = idx / CO; int k = rem % K; int ci = rem / K;
    wr[idx] = w[((size_t)o * CI + ci) * K + k];
}

__global__ void repack_all(const float* w1, const float* w2, const float* w3,
                           const float* w4, const float* w5, const float* w6,
                           const float* w7,
                           unsigned short* p1, unsigned short* p2,
                           unsigned short* p3, unsigned short* p4,
                           unsigned short* p5, float* r6, float* r7)
{
    int idx = blockIdx.x * 256 + threadIdx.x;
    if (idx < 122880) { repack_img(w1, p1, idx, 16, 10, 40); return; }
    idx -= 122880;
    if (idx < 147456) { repack_img(w2, p2, idx, 8, 5, 96); return; }
    idx -= 147456;
    if (idx < 147456) { repack_img(w3, p3, idx, 8, 5, 96); return; }
    idx -= 147456;
    if (idx < 147456) { repack_img(w4, p4, idx, 8, 5, 96); return; }
    idx -= 147456;
    if (idx < 147456) { repack_img(w5, p5, idx, 8, 5, 96); return; }
    idx -= 147456;
    if (idx < 46080)  { repack_okc(w6, r6, idx, 96, 5, 96); return; }
    idx -= 46080;
    if (idx < 36864)  { repack_okc(w7, r7, idx, 96, 3, 128); return; }
}

// ---------------------------------------------------------------------------
// conv6: 96->96, K=5, s=2, 62->29, relu.  Grid 256 = 64 samples x 4 o-blocks.
// ---------------------------------------------------------------------------
__global__ __launch_bounds__(256)
void conv6_k(const float* __restrict__ y5p, const float* __restrict__ w6r,
             const float* __restrict__ b6, float* __restrict__ y6)
{
    __shared__ float s5[96 * 62];
    const int b = blockIdx.x >> 2, ob = blockIdx.x & 3;
    const int tid = threadIdx.x;
    for (int i = tid; i < 96 * 62; i += 256) s5[i] = y5p[(size_t)b * 96 * 62 + i];
    __syncthreads();

    const int wave = __builtin_amdgcn_readfirstlane(tid >> 6);
    const int t = tid & 63;
    if (t < 29) {
        const int o0 = ob * 24 + wave * 6;
        float a[6];
        #pragma unroll
        for (int oo = 0; oo < 6; oo++) a[oo] = 0.f;
        for (int ci = 0; ci < 96; ci++) {
            float xr[5];
            #pragma unroll
            for (int k = 0; k < 5; k++) xr[k] = s5[ci * 62 + 2 * t + k];
            #pragma unroll
            for (int k = 0; k < 5; k++) {
                const float* wp = w6r + (ci * 5 + k) * 96 + o0;   // wave-uniform
                #pragma unroll
                for (int oo = 0; oo < 6; oo++)
                    a[oo] = fmaf(wp[oo], xr[k], a[oo]);
            }
        }
        #pragma unroll
        for (int oo = 0; oo < 6; oo++)
            y6[((size_t)b * 96 + o0 + oo) * 29 + t] = fmaxf(a[oo] + b6[o0 + oo], 0.f);
    }
}

// ---------------------------------------------------------------------------
// tail2: conv7 (96->128, K=3, s=2, 29->14, relu) + masked max + MLP head.
// ---------------------------------------------------------------------------
__global__ __launch_bounds__(256)
void tail2(const float* __restrict__ y6,
           const float* __restrict__ w7r, const float* __restrict__ b7,
           const int* __restrict__ lens,
           const float* __restrict__ lw1, const float* __restrict__ lb1,
           const float* __restrict__ lw2, const float* __restrict__ lb2,
           const float* __restrict__ lw3, const float* __restrict__ lb3,
           float* __restrict__ out)
{
    __shared__ float s6[96 * 29 + 8];     // +8: benign overread slack (tl>=14)
    __shared__ float s7[128 * 14];
    __shared__ float feat[128], h1[128], h2[64];

    const int b = blockIdx.x, tid = threadIdx.x;
    for (int i = tid; i < 96 * 29; i += 256) s6[i] = y6[(size_t)b * 96 * 29 + i];
    __syncthreads();

    const int wave = __builtin_amdgcn_readfirstlane(tid >> 6);
    const int lane = tid & 63;
    const int sub  = lane >> 4;           // ci quarter
    const int tl   = lane & 15;           // t (active tl<14)
    {
        float a[32];
        #pragma unroll
        for (int oo = 0; oo < 32; oo++) a[oo] = 0.f;
        const int ci0 = sub * 24;
        for (int ci = ci0; ci < ci0 + 24; ci++) {
            float xr[3];
            #pragma unroll
            for (int k = 0; k < 3; k++) xr[k] = s6[ci * 29 + 2 * tl + k];
            #pragma unroll
            for (int k = 0; k < 3; k++) {
                const float* wp = w7r + (ci * 3 + k) * 128 + wave * 32;  // uniform
                #pragma unroll
                for (int oo = 0; oo < 32; oo++)
                    a[oo] = fmaf(wp[oo], xr[k], a[oo]);
            }
        }
        #pragma unroll
        for (int oo = 0; oo < 32; oo++) {
            float v = a[oo];
            v += __shfl_xor(v, 16, 64);
            v += __shfl_xor(v, 32, 64);
            if (sub == 0 && tl < 14) {
                int o = wave * 32 + oo;
                s7[o * 14 + tl] = fmaxf(v + b7[o], 0.f);
            }
        }
    }
    __syncthreads();

    if (tid < 128) {
        int L = lens[b];
        L = (L - 10) / 2 + 1;
        L = (L - 5) / 2 + 1;
        L = (L - 5) / 2 + 1;
        L = (L - 5) / 2 + 1;
        L = L / 2;
        L = (L - 5) / 2 + 1;
        L = L / 2;
        L = (L - 5) / 2 + 1;
        L = (L - 3) / 2 + 1;
        float m = -INFINITY;
        for (int t = 0; t < L; t++) m = fmaxf(m, s7[tid * 14 + t]);
        feat[tid] = m;
    }
    __syncthreads();

    if (tid < 128) {
        float s = lb1[tid];
        for (int i = 0; i < 128; i++) s = fmaf(lw1[tid * 128 + i], feat[i], s);
        h1[tid] = fmaxf(s, 0.f);
    }
    __syncthreads();
    if (tid < 64) {
        float s = lb2[tid];
        for (int i = 0; i < 128; i++) s = fmaf(lw2[tid * 128 + i], h1[i], s);
        h2[tid] = fmaxf(s, 0.f);
    }
    __syncthreads();
    if (tid < 5) {
        float s = lb3[tid];
        for (int i = 0; i < 64; i++) s = fmaf(lw3[tid * 64 + i], h2[i], s);
        out[b * 5 + tid] = s;
    }
}

extern "C" void kernel_launch(void* const* d_in, const int* in_sizes, int n_in,
                              void* d_out, int out_size, void* d_ws, size_t ws_size,
                              hipStream_t stream)
{
    const float* x    = (const float*)d_in[0];
    const int*   lens = (const int*)  d_in[1];
    const float* w1 = (const float*)d_in[2];   const float* b1 = (const float*)d_in[3];
    const float* w2 = (const float*)d_in[4];   const float* b2 = (const float*)d_in[5];
    const float* w3 = (const float*)d_in[6];   const float* b3 = (const float*)d_in[7];
    const float* w4 = (const float*)d_in[8];   const float* b4 = (const float*)d_in[9];
    const float* w5 = (const float*)d_in[10];  const float* b5 = (const float*)d_in[11];
    const float* w6 = (const float*)d_in[12];  const float* b6 = (const float*)d_in[13];
    const float* w7 = (const float*)d_in[14];  const float* b7 = (const float*)d_in[15];
    const float* lw1 = (const float*)d_in[16]; const float* lb1 = (const float*)d_in[17];
    const float* lw2 = (const float*)d_in[18]; const float* lb2 = (const float*)d_in[19];
    const float* lw3 = (const float*)d_in[20]; const float* lb3 = (const float*)d_in[21];
    float* out = (float*)d_out;
    char*  W   = (char*)d_ws;

    // lengths: 8192 -> 4092 -> 2044 -> 1020 -> 508 -> 254 -> 125 -> 62 -> 29 -> 14
    size_t off = 0;
    auto take = [&](size_t bytes) {
        size_t o = off; off = (off + bytes + 255) & ~(size_t)255; return o;
    };
    size_t o_y3h = take(((size_t)64 * 96 * 1020 + 2048) * 2);
    size_t o_y4h = take(((size_t)64 * 96 * 254 + 2048) * 2);   // fp16 pooled
    size_t o_y5p = take((size_t)64 * 96 * 62 * 4 + 1024);      // fp32 pooled
    size_t o_y6  = take((size_t)64 * 96 * 29 * 4);
    size_t o_wp1 = take((size_t)122880 * 2);
    size_t o_wp2 = take((size_t)147456 * 2);
    size_t o_wp3 = take((size_t)147456 * 2);
    size_t o_wp4 = take((size_t)147456 * 2);
    size_t o_wp5 = take((size_t)147456 * 2);
    size_t o_w6r = take((size_t)46080 * 4);
    size_t o_w7r = take((size_t)36864 * 4);
    size_t persist = off;

    auto chunk_bytes = [&](int Bc) -> size_t {
        size_t s = 0;
        s += ((size_t)Bc * 96 * 4092 + 2048) * 2 + 256;
        s += ((size_t)Bc * 96 * 2044 + 2048) * 2 + 256;
        return s;
    };
    int Bc = 64;
    while (Bc > 1 && persist + chunk_bytes(Bc) > ws_size) Bc >>= 1;
    size_t o_y1h = take(((size_t)Bc * 96 * 4092 + 2048) * 2);
    size_t o_y2h = take(((size_t)Bc * 96 * 2044 + 2048) * 2);

    auto US = [&](size_t o) { return (unsigned short*)(W + o); };
    auto FP = [&](size_t o) { return (float*)(W + o); };

    // one repack kernel (795648 elements)
    repack_all<<<dim3((795648 + 255) / 256), 256, 0, stream>>>(
        w1, w2, w3, w4, w5, w6, w7,
        US(o_wp1), US(o_wp2), US(o_wp3), US(o_wp4), US(o_wp5),
        FP(o_w6r), FP(o_w7r));

    const int nchunks = 64 / Bc;
    for (int c = 0; c < nchunks; c++) {
        const float* xc = x + (size_t)c * Bc * 40 * 8192;

        // conv1: fp32 in (fused convert), KP=16, NBLK=256 -> nT=16
        conv_mfma10<16, 40, 256, true, true, true, false><<<dim3(Bc * 16), 256, 0, stream>>>(
            (const unsigned short*)xc, US(o_wp1), b1, US(o_y1h), nullptr, 8192, 4092);
        // conv2: KP=8, NBLK=256 -> nT=8
        conv_mfma10< 8, 96, 256, false, true, true, false><<<dim3(Bc * 8), 256, 0, stream>>>(
            US(o_y1h), US(o_wp2), b2, US(o_y2h), nullptr, 4092, 2044);
        // conv3: KP=8, NBLK=128 -> nT=8
        unsigned short* y3h_c = US(o_y3h) + (size_t)c * Bc * 96 * 1020;
        conv_mfma10< 8, 96, 128, false, true, true, false><<<dim3(Bc * 8), 256, 0, stream>>>(
            US(o_y2h), US(o_wp3), b3, y3h_c, nullptr, 2044, 1020);
    }

    // conv4: NBLK=128 -> nT=4; fused AvgPool2+ReLU -> y4h (fp16, T=254)
    conv_mfma10<8, 96, 128, false, false, true, true><<<dim3(64 * 4), 256, 0, stream>>>(
        US(o_y3h), US(o_wp4), b4, US(o_y4h), nullptr, 1020, 508);

    // conv5 (MFMA): NBLK=64 -> nT=2; fused AvgPool2+ReLU -> y5p (fp32, T=62)
    conv_mfma10<8, 96, 64, false, false, false, true><<<dim3(64 * 2), 256, 0, stream>>>(
        US(o_y4h), US(o_wp5), b5, nullptr, FP(o_y5p), 254, 125);

    // conv6: grid 256 (64 samples x 4 o-blocks)
    conv6_k<<<dim3(256), 256, 0, stream>>>(FP(o_y5p), FP(o_w6r), b6, FP(o_y6));

    // conv7 + masked max + MLP head
    tail2<<<dim3(64), 256, 0, stream>>>(
        FP(o_y6), FP(o_w7r), b7, lens, lw1, lb1, lw2, lb2, lw3, lb3, out);
}